// Round 10
// baseline (225.938 us; speedup 1.0000x reference)
//
#include <hip/hip_runtime.h>

typedef unsigned short u16;
typedef unsigned char u8;
typedef __attribute__((ext_vector_type(8))) short short8;
typedef __attribute__((ext_vector_type(2))) float f32x2;
typedef __attribute__((ext_vector_type(4))) float f32x4;
typedef __attribute__((ext_vector_type(4))) int i32x4;
typedef __attribute__((ext_vector_type(2))) int i32x2;
typedef __attribute__((ext_vector_type(4))) unsigned short us4;
typedef __attribute__((ext_vector_type(8))) unsigned short us8;
typedef __attribute__((ext_vector_type(4))) unsigned int u32x4;

#define N_NODES 50000
#define N_EDGES 800000
#define DIM 128
#define NINV (1.0f / 50000.0f)
#define SROW 136      /* LDS row stride (u16) */
#define NBKT 3125     /* node groups of 16: 50000/16 */
#define CAP 512       /* per-group capacity; mean 256, P(overflow) ~ e^-99 */
#define SUPN 800      /* nodes per superkey (50 groups) */
#define NSUP 63       /* ceil(50000/800); last superkey has 400 nodes */
#define SEGCAP 16384  /* segment entries per superkey; mean 12800, ~31 sigma margin */

__device__ __forceinline__ float bf2f(u16 u) {
    union { unsigned int i; float f; } v; v.i = ((unsigned int)u) << 16; return v.f;
}
__device__ __forceinline__ u16 f2bf(float f) {
    union { float f; unsigned int i; } v; v.f = f;
    return (u16)((v.i + 0x7FFFu + ((v.i >> 16) & 1u)) >> 16);
}

// ---------------- prep: pack B1/B2, split x, LDS-binned segmented edge bucketing ----
// blocks 0..15: pack B1; 16..31: pack B2; 32..32+splitB-1: split x (bf16 + fp8);
// rest (782): 1024 edges/block. LDS-bin into 63 superkeys (hist+scan+scatter),
// ONE segment-reserve global atomic per non-empty (block, superkey) (~50K total),
// then coalesced run-writes into per-superkey segments.
// Entry = src<<10 | (dst - superkey*800)  (16+10 bits).
__global__ __launch_bounds__(256) void k_prep(
        const float* __restrict__ W1l, const float* __restrict__ W1r, u16* __restrict__ Bp1,
        const float* __restrict__ W2l, const float* __restrict__ W2r, u16* __restrict__ Bp2,
        const float* __restrict__ x, u16* __restrict__ xh, u8* __restrict__ xf8,
        const int* __restrict__ esrc, const int* __restrict__ edst,
        int* __restrict__ segCnt, unsigned* __restrict__ segBuf, int splitB) {
    int b = blockIdx.x;
    if (b < 32) {
        const float* Wl = (b < 16) ? W1l : W2l;
        const float* Wr = (b < 16) ? W1r : W2r;
        u16* Bp = (b < 16) ? Bp1 : Bp2;
        int idx = (b & 15) * 256 + threadIdx.x;      // 0..4095
        int lane = idx & 63;
        int kc = (idx >> 6) & 7;
        int nt = idx >> 9;
        int q = lane >> 4, nn = lane & 15;
        int col = nt * 16 + nn;
        #pragma unroll
        for (int j = 0; j < 8; ++j) {
            int k = kc * 32 + q * 8 + j;
            float v = (k < 128) ? Wl[k * 128 + col] : Wr[(k - 128) * 128 + col];
            Bp[(long)idx * 8 + j] = f2bf(v);
        }
    } else if (b < 32 + splitB) {
        long i4 = ((long)(b - 32) * 256 + threadIdx.x) * 4;
        f32x4 v = *(const f32x4*)(x + i4);
        us4 h;
        #pragma unroll
        for (int j = 0; j < 4; ++j) h[j] = f2bf(v[j]);
        *(us4*)(xh + i4) = h;
        int p = __builtin_amdgcn_cvt_pk_fp8_f32(v[0], v[1], 0, false);
        p = __builtin_amdgcn_cvt_pk_fp8_f32(v[2], v[3], p, true);
        *(int*)(xf8 + i4) = p;
    } else {
        __shared__ int sHistB[64], sScanB[64], sCurB[64], sBaseB[64];
        __shared__ unsigned sStage[1024];
        __shared__ u8 sBinOf[1024];
        int tid = threadIdx.x;
        int hb = b - 32 - splitB;
        int e4 = hb * 1024 + tid * 4;
        bool val = e4 < N_EDGES;       // N_EDGES % 4 == 0: all-or-nothing per thread
        if (tid < 64) sHistB[tid] = 0;
        __syncthreads();
        unsigned ent[4]; int bin[4];
        if (val) {
            i32x4 d4 = *(const i32x4*)(edst + e4);
            i32x4 s4 = *(const i32x4*)(esrc + e4);
            #pragma unroll
            for (int j = 0; j < 4; ++j) {
                unsigned dd = (unsigned)d4[j];
                int bi = (int)(dd / 800u);
                bin[j] = bi;
                ent[j] = ((unsigned)s4[j] << 10) | (dd - (unsigned)bi * 800u);
                atomicAdd(&sHistB[bi], 1);
            }
        }
        __syncthreads();
        if (tid == 0) {
            int acc = 0;
            #pragma unroll
            for (int i = 0; i < 64; ++i) { sScanB[i] = acc; sCurB[i] = acc; acc += sHistB[i]; }
        }
        __syncthreads();
        if (val) {
            #pragma unroll
            for (int j = 0; j < 4; ++j) {
                int p = atomicAdd(&sCurB[bin[j]], 1);
                sStage[p] = ent[j];
                sBinOf[p] = (u8)bin[j];
            }
        }
        __syncthreads();
        if (tid < 64) {
            int c = sHistB[tid];
            sBaseB[tid] = c ? atomicAdd(&segCnt[tid << 4], c) : 0;
        }
        __syncthreads();
        int tcount = sScanB[63] + sHistB[63];
        for (int p = tid; p < tcount; p += 256) {
            int bn = sBinOf[p];
            long ofs = (long)sBaseB[bn] + (p - sScanB[bn]);
            if (ofs < SEGCAP)
                segBuf[(long)bn * SEGCAP + ofs] = sStage[p];
        }
    }
}

// ---------------- per-superkey counting sort -> col_srt (group-CAP layout) + hdr ----
__global__ __launch_bounds__(512) void k_sort(
        const int* __restrict__ segCnt, const unsigned* __restrict__ segBuf,
        u16* __restrict__ col_srt, u16* __restrict__ hdr) {
    __shared__ int sHist[SUPN], sStart[SUPN], sCur[SUPN];
    int tid = threadIdx.x;
    int s = blockIdx.x;
    int nnodes = N_NODES - s * SUPN; if (nnodes > SUPN) nnodes = SUPN;
    int ngroups = nnodes >> 4;
    int n = segCnt[s << 4]; if (n > SEGCAP) n = SEGCAP;
    for (int i = tid; i < SUPN; i += 512) { sHist[i] = 0; sCur[i] = 0; }
    __syncthreads();
    const unsigned* seg = segBuf + (long)s * SEGCAP;
    unsigned ent[32];
    #pragma unroll
    for (int i = 0; i < 32; ++i) {
        int idx = i * 512 + tid;                 // coalesced
        ent[i] = (idx < n) ? seg[idx] : 0xFFFFFFFFu;
    }
    #pragma unroll
    for (int i = 0; i < 32; ++i)
        if (ent[i] != 0xFFFFFFFFu) atomicAdd(&sHist[ent[i] & 1023u], 1);
    __syncthreads();
    if (tid < ngroups) {
        int base = 0;
        int gb = (s * 50 + tid) * 32;
        #pragma unroll
        for (int i = 0; i < 16; ++i) {
            int node = tid * 16 + i;
            int d = sHist[node];
            int st_c = base < CAP ? base : CAP;
            int en_c = base + d < CAP ? base + d : CAP;
            sStart[node] = base;
            hdr[gb + i] = (u16)st_c;
            hdr[gb + 16 + i] = (u16)(en_c - st_c);
            base += d;
        }
    }
    __syncthreads();
    #pragma unroll
    for (int i = 0; i < 32; ++i) {
        unsigned e = ent[i];
        if (e != 0xFFFFFFFFu) {
            int node = (int)(e & 1023u);
            int pos = atomicAdd(&sCur[node], 1);
            int ofs = sStart[node] + pos;
            if (ofs < CAP)
                col_srt[(long)(s * 50 + (node >> 4)) * CAP + ofs] = (u16)(e >> 10);
        }
    }
}

// decode 16 fp8 + accumulate — packed f32x2 path (v_pk_add_f32)
__device__ __forceinline__ void acc_row16(u32x4 w, f32x2 sum2[8]) {
    #pragma unroll
    for (int h = 0; h < 4; ++h) {
        sum2[2 * h]     += __builtin_amdgcn_cvt_pk_f32_fp8((int)w[h], false);
        sum2[2 * h + 1] += __builtin_amdgcn_cvt_pk_f32_fp8((int)w[h], true);
    }
}

// ---------------- fused AGG + GEMM + BN-stats (512 threads) ----------------
// phase 1: 32 lanes/node (4 strided edge-quarters x 8 dim-groups) -> serial chain
//          per lane is deg/4 (~4 rows = ONE 4-in-flight batch for typical nodes).
// phase 2: 8 waves x one 16-col MFMA tile.
__global__ __launch_bounds__(512) void k_ag(
        const u8* __restrict__ fq, const u16* __restrict__ fh,
        const u16* __restrict__ hdr, const u16* __restrict__ col_srt,
        const u16* __restrict__ Bph, const float* __restrict__ bias,
        u16* __restrict__ h16, float* __restrict__ stats) {
    __shared__ u16 sA[16 * SROW];
    __shared__ __align__(16) u16 sIdx[CAP];
    int tid = threadIdx.x;
    long nodebase = (long)blockIdx.x * 16;       // 3125*16 == 50000 exact

    // stage sorted index list (1KB) into LDS
    if (tid < 64)
        *(us8*)(sIdx + tid * 8) = *(const us8*)(col_srt + (long)blockIdx.x * CAP + tid * 8);
    __syncthreads();

    // ---- phase 1: gather-mean (fp8, 16B/lane, 4-way strided edge split) ----
    {
        int grp = tid >> 5;          // node 0..15
        int s5  = tid & 31;
        int sub = s5 >> 3;           // edge quarter 0..3 (strided)
        int d16 = (s5 & 7) * 16;     // dim base
        int st  = hdr[blockIdx.x * 32 + grp];
        int deg = hdr[blockIdx.x * 32 + 16 + grp];
        int s = st, e = st + deg;
        f32x2 sum2[8];
        #pragma unroll
        for (int p = 0; p < 8; ++p) sum2[p] = (f32x2){0.f, 0.f};
        int j = s + sub;
        for (; j + 12 < e; j += 16) {        // 4 loads in flight
            int i0 = sIdx[j], i1 = sIdx[j + 4], i2 = sIdx[j + 8], i3 = sIdx[j + 12];
            u32x4 w0 = *(const u32x4*)(fq + (long)i0 * DIM + d16);
            u32x4 w1 = *(const u32x4*)(fq + (long)i1 * DIM + d16);
            u32x4 w2 = *(const u32x4*)(fq + (long)i2 * DIM + d16);
            u32x4 w3 = *(const u32x4*)(fq + (long)i3 * DIM + d16);
            acc_row16(w0, sum2);
            acc_row16(w1, sum2);
            acc_row16(w2, sum2);
            acc_row16(w3, sum2);
        }
        for (; j < e; j += 4) {
            int i0 = sIdx[j];
            u32x4 w0 = *(const u32x4*)(fq + (long)i0 * DIM + d16);
            acc_row16(w0, sum2);
        }
        // combine 4 quarters (xor 8 and 16 stay within the node's 32 lanes)
        #pragma unroll
        for (int p = 0; p < 8; ++p) {
            sum2[p][0] += __shfl_xor(sum2[p][0], 8);
            sum2[p][1] += __shfl_xor(sum2[p][1], 8);
            sum2[p][0] += __shfl_xor(sum2[p][0], 16);
            sum2[p][1] += __shfl_xor(sum2[p][1], 16);
        }
        if (sub == 0) {
            float dn = (deg > 0) ? 1.f / (float)deg : 1.f;
            us8 r0, r1;
            #pragma unroll
            for (int k = 0; k < 8; ++k) {
                r0[k] = f2bf(sum2[k >> 1][k & 1] * dn);          // dims d16+0..7
                r1[k] = f2bf(sum2[4 + (k >> 1)][k & 1] * dn);    // dims d16+8..15
            }
            *(us8*)(sA + grp * SROW + d16) = r0;
            *(us8*)(sA + grp * SROW + d16 + 8) = r1;
        }
    }
    __syncthreads();

    // ---- phase 2: MFMA, 8 waves x one 16-col tile ----
    int cg = tid >> 6, lane = tid & 63;
    int q = lane >> 4, nn = lane & 15;
    long rc = nodebase + nn;

    short8 ah[8];
    #pragma unroll
    for (int kc = 0; kc < 4; ++kc)
        ah[kc] = *(const short8*)(sA + nn * SROW + kc * 32 + q * 8);
    #pragma unroll
    for (int kc = 0; kc < 4; ++kc) {
        int ko = kc * 32 + q * 8;
        us8 rv = *(const us8*)(fh + rc * DIM + ko);
        short8 t;
        #pragma unroll
        for (int j = 0; j < 8; ++j) t[j] = (short)rv[j];
        ah[4 + kc] = t;
    }

    f32x4 acc = (f32x4){0.f, 0.f, 0.f, 0.f};
    #pragma unroll
    for (int kc = 0; kc < 8; ++kc) {
        short8 bh = *(const short8*)(Bph + (((cg * 8 + kc) * 64 + lane) << 3));
        acc = __builtin_amdgcn_mfma_f32_16x16x32_bf16(ah[kc], bh, acc, 0, 0, 0);
    }

    int bank = blockIdx.x & 7;
    int col = cg * 16 + nn;
    float bv = bias[col];
    float ps = 0.f, pq = 0.f;
    #pragma unroll
    for (int r = 0; r < 4; ++r) {
        float v = acc[r] + bv;
        long idx = (nodebase + q * 4 + r) * DIM + col;
        h16[idx] = f2bf(v);
        ps += v; pq += v * v;
    }
    ps += __shfl_xor(ps, 16);
    ps += __shfl_xor(ps, 32);
    pq += __shfl_xor(pq, 16);
    pq += __shfl_xor(pq, 32);
    if (q == 0) {
        atomicAdd(&stats[bank * 512 + col], ps);
        atomicAdd(&stats[bank * 512 + 256 + col], pq);
    }
}

// ---------------- h_act = relu(bn1(h1)) once per node -> bf16 (root) + fp8 (gather) ----
__global__ __launch_bounds__(256) void k_act(
        const u16* __restrict__ h, const float* __restrict__ stats,
        const float* __restrict__ g, const float* __restrict__ bt,
        u16* __restrict__ outh, u8* __restrict__ outq) {
    __shared__ float acS[256];
    int tid = threadIdx.x;
    if (tid < 128) {
        float s = 0.f, qq = 0.f;
        #pragma unroll
        for (int b = 0; b < 8; ++b) {
            s  += stats[b * 512 + tid];
            qq += stats[b * 512 + 256 + tid];
        }
        float mu = s * NINV;
        float var = qq * NINV - mu * mu;
        float a = g[tid] * rsqrtf(var + 1e-5f);
        acS[tid] = a;
        acS[128 + tid] = bt[tid] - mu * a;
    }
    __syncthreads();
    long i8 = ((long)blockIdx.x * 256 + tid) * 8;
    int c = (int)(i8 & 127);
    us8 hv = *(const us8*)(h + i8);
    us8 r;
    float v[8];
    #pragma unroll
    for (int j = 0; j < 8; ++j) {
        float t = bf2f(hv[j]) * acS[c + j] + acS[128 + c + j];
        t = t > 0.f ? t : 0.f;
        v[j] = t;
        r[j] = f2bf(t);
    }
    *(us8*)(outh + i8) = r;
    int p0 = __builtin_amdgcn_cvt_pk_fp8_f32(v[0], v[1], 0, false);
    p0 = __builtin_amdgcn_cvt_pk_fp8_f32(v[2], v[3], p0, true);
    int p1 = __builtin_amdgcn_cvt_pk_fp8_f32(v[4], v[5], 0, false);
    p1 = __builtin_amdgcn_cvt_pk_fp8_f32(v[6], v[7], p1, true);
    i32x2 pp; pp[0] = p0; pp[1] = p1;
    *(i32x2*)(outq + i8) = pp;
}

// out = relu(bn(h)+x); coeffs computed in-block from banked stats
__global__ __launch_bounds__(256) void k_bn_add_relu(
        const u16* __restrict__ h, const float* __restrict__ stats,
        const float* __restrict__ g, const float* __restrict__ bt,
        const float* __restrict__ x, float* __restrict__ outv) {
    __shared__ float acS[256];
    int tid = threadIdx.x;
    if (tid < 128) {
        float s = 0.f, qq = 0.f;
        #pragma unroll
        for (int b = 0; b < 8; ++b) {
            s  += stats[b * 512 + tid];
            qq += stats[b * 512 + 256 + tid];
        }
        float mu = s * NINV;
        float var = qq * NINV - mu * mu;
        float a = g[tid] * rsqrtf(var + 1e-5f);
        acS[tid] = a;
        acS[128 + tid] = bt[tid] - mu * a;
    }
    __syncthreads();
    long i8 = ((long)blockIdx.x * 256 + tid) * 8;
    int c = (int)(i8 & 127);
    us8 hv = *(const us8*)(h + i8);
    f32x4 x0 = *(const f32x4*)(x + i8);
    f32x4 x1 = *(const f32x4*)(x + i8 + 4);
    f32x4 r0, r1;
    #pragma unroll
    for (int j = 0; j < 4; ++j) {
        float v = bf2f(hv[j]) * acS[c + j] + acS[128 + c + j] + x0[j];
        r0[j] = v > 0.f ? v : 0.f;
        float w = bf2f(hv[4 + j]) * acS[c + 4 + j] + acS[128 + c + 4 + j] + x1[j];
        r1[j] = w > 0.f ? w : 0.f;
    }
    *(f32x4*)(outv + i8) = r0;
    *(f32x4*)(outv + i8 + 4) = r1;
}

extern "C" void kernel_launch(void* const* d_in, const int* in_sizes, int n_in,
                              void* d_out, int out_size, void* d_ws, size_t ws_size,
                              hipStream_t stream) {
    (void)in_sizes; (void)n_in; (void)out_size; (void)ws_size;
    const float* x   = (const float*)d_in[0];
    const int*   ei  = (const int*)d_in[1];
    const float* W1l = (const float*)d_in[2];
    const float* b1  = (const float*)d_in[3];
    const float* W1r = (const float*)d_in[4];
    const float* g1  = (const float*)d_in[5];
    const float* bt1 = (const float*)d_in[6];
    const float* W2l = (const float*)d_in[7];
    const float* b2  = (const float*)d_in[8];
    const float* W2r = (const float*)d_in[9];
    const float* g2  = (const float*)d_in[10];
    const float* bt2 = (const float*)d_in[11];
    float* out = (float*)d_out;

    const int* esrc = ei;
    const int* edst = ei + N_EDGES;

    char* ws = (char*)d_ws;
    size_t off = 0;
    auto alloc = [&](size_t bytes) { size_t p = off; off = (off + bytes + 255) & ~(size_t)255; return p; };
    float* stats1  = (float*)(ws + alloc(4096 * 4));   // 8 banks x 512 (sum@+col, sumsq@+256+col)
    float* stats2  = (float*)(ws + alloc(4096 * 4));
    int*   segCnt  = (int*)  (ws + alloc(64 * 16 * 4));   // 1 counter per 64B line
    size_t zero_bytes = off;                       // everything above must be zeroed
    unsigned* segBuf = (unsigned*)(ws + alloc((size_t)NSUP * SEGCAP * 4));
    u16*   col_srt = (u16*)  (ws + alloc((size_t)NBKT * CAP * 2));
    u16*   hdr     = (u16*)  (ws + alloc((size_t)NBKT * 32 * 2));
    u16*   xh      = (u16*)  (ws + alloc((size_t)N_NODES * DIM * 2));
    u8*    xf8     = (u8*)   (ws + alloc((size_t)N_NODES * DIM));
    u16*   hb1     = (u16*)  (ws + alloc((size_t)N_NODES * DIM * 2));  // raw h1 bf16
    u16*   hah     = (u16*)  (ws + alloc((size_t)N_NODES * DIM * 2));  // h_act bf16
    u8*    haf8    = (u8*)   (ws + alloc((size_t)N_NODES * DIM));     // h_act fp8
    u16*   hb2     = (u16*)  (ws + alloc((size_t)N_NODES * DIM * 2));  // raw h2 bf16
    u16*   Bp1h    = (u16*)  (ws + alloc(256 * 128 * 2));
    u16*   Bp2h    = (u16*)  (ws + alloc(256 * 128 * 2));

    hipMemsetAsync(ws, 0, zero_bytes, stream);

    const int AGB = N_NODES / 16;                    // 3125 exact
    const int EWB4 = (int)(((long)N_NODES * DIM) / 1024);  // 6250 exact
    const int EWB8 = (int)(((long)N_NODES * DIM) / 2048);  // 3125 exact
    const int EDGB = (N_EDGES + 1023) / 1024;        // 782 (4 edges/thread)
    const int PREPB = 32 + EWB4 + EDGB;              // pack + split + binned append

    // prep: pack both B + split x (bf16 + fp8) + LDS-binned segmented bucketing
    k_prep<<<PREPB, 256, 0, stream>>>(W1l, W1r, Bp1h, W2l, W2r, Bp2h, x, xh, xf8,
                                      esrc, edst, segCnt, segBuf, EWB4);

    // per-superkey counting sort -> col_srt (group-CAP layout) + hdr
    k_sort<<<NSUP, 512, 0, stream>>>(segCnt, segBuf, col_srt, hdr);

    // stage 1: fused agg+gemm on x (fp8 gather, bf16 root); writes h1 bf16 + stats1
    k_ag<<<AGB, 512, 0, stream>>>(xf8, xh, hdr, col_srt, Bp1h, b1, hb1, stats1);

    // h_act = relu(bn1(h1)) once per node -> bf16 + fp8
    k_act<<<EWB8, 256, 0, stream>>>(hb1, stats1, g1, bt1, hah, haf8);

    // stage 2: fused agg+gemm on h_act; writes h2 bf16 + stats2
    k_ag<<<AGB, 512, 0, stream>>>(haf8, hah, hdr, col_srt, Bp2h, b2, hb2, stats2);

    // epilogue: out = relu(bn(h2) + x), coeffs from stats2
    k_bn_add_relu<<<EWB8, 256, 0, stream>>>(hb2, stats2, g2, bt2, x, out);
}

// Round 11
// 199.057 us; speedup vs baseline: 1.1350x; 1.1350x over previous
//
#include <hip/hip_runtime.h>

typedef unsigned short u16;
typedef unsigned char u8;
typedef __attribute__((ext_vector_type(8))) short short8;
typedef __attribute__((ext_vector_type(2))) float f32x2;
typedef __attribute__((ext_vector_type(4))) float f32x4;
typedef __attribute__((ext_vector_type(4))) int i32x4;
typedef __attribute__((ext_vector_type(2))) int i32x2;
typedef __attribute__((ext_vector_type(4))) unsigned short us4;
typedef __attribute__((ext_vector_type(8))) unsigned short us8;
typedef __attribute__((ext_vector_type(4))) unsigned int u32x4;

#define N_NODES 50000
#define N_EDGES 800000
#define DIM 128
#define NINV (1.0f / 50000.0f)
#define SROW 136      /* LDS row stride (u16) */
#define NBKT 3125     /* node groups of 16: 50000/16 */
#define CAP 512       /* per-group capacity; mean 256, P(overflow) ~ e^-99 */
#define SUPN 800      /* nodes per superkey (50 groups) */
#define NSUP 63       /* ceil(50000/800); last superkey has 400 nodes */
#define SEGCAP 16384  /* segment entries per superkey; mean 12800, ~31 sigma margin */

__device__ __forceinline__ float bf2f(u16 u) {
    union { unsigned int i; float f; } v; v.i = ((unsigned int)u) << 16; return v.f;
}
__device__ __forceinline__ u16 f2bf(float f) {
    union { float f; unsigned int i; } v; v.f = f;
    return (u16)((v.i + 0x7FFFu + ((v.i >> 16) & 1u)) >> 16);
}

// ---------------- prep: pack B1/B2, split x, LDS-binned segmented edge bucketing ----
// blocks 0..15: pack B1; 16..31: pack B2; 32..32+splitB-1: split x (8 floats/thread);
// rest (391): 2048 edges/block (8/thread). LDS-bin into 63 superkeys with a
// wave-parallel shfl_up scan; ONE segment-reserve global atomic per non-empty
// (block, superkey) (~25K total), reserve latency hidden under LDS scatter;
// coalesced run-writes into per-superkey segments.
// Entry = src<<10 | (dst - superkey*800)  (16+10 bits).
__global__ __launch_bounds__(256) void k_prep(
        const float* __restrict__ W1l, const float* __restrict__ W1r, u16* __restrict__ Bp1,
        const float* __restrict__ W2l, const float* __restrict__ W2r, u16* __restrict__ Bp2,
        const float* __restrict__ x, u16* __restrict__ xh, u8* __restrict__ xf8,
        const int* __restrict__ esrc, const int* __restrict__ edst,
        int* __restrict__ segCnt, unsigned* __restrict__ segBuf, int splitB) {
    int b = blockIdx.x;
    if (b < 32) {
        const float* Wl = (b < 16) ? W1l : W2l;
        const float* Wr = (b < 16) ? W1r : W2r;
        u16* Bp = (b < 16) ? Bp1 : Bp2;
        int idx = (b & 15) * 256 + threadIdx.x;      // 0..4095
        int lane = idx & 63;
        int kc = (idx >> 6) & 7;
        int nt = idx >> 9;
        int q = lane >> 4, nn = lane & 15;
        int col = nt * 16 + nn;
        #pragma unroll
        for (int j = 0; j < 8; ++j) {
            int k = kc * 32 + q * 8 + j;
            float v = (k < 128) ? Wl[k * 128 + col] : Wr[(k - 128) * 128 + col];
            Bp[(long)idx * 8 + j] = f2bf(v);
        }
    } else if (b < 32 + splitB) {
        long i8 = ((long)(b - 32) * 256 + threadIdx.x) * 8;
        f32x4 v0 = *(const f32x4*)(x + i8);
        f32x4 v1 = *(const f32x4*)(x + i8 + 4);
        us8 h;
        #pragma unroll
        for (int j = 0; j < 4; ++j) { h[j] = f2bf(v0[j]); h[4 + j] = f2bf(v1[j]); }
        *(us8*)(xh + i8) = h;
        int p0 = __builtin_amdgcn_cvt_pk_fp8_f32(v0[0], v0[1], 0, false);
        p0 = __builtin_amdgcn_cvt_pk_fp8_f32(v0[2], v0[3], p0, true);
        int p1 = __builtin_amdgcn_cvt_pk_fp8_f32(v1[0], v1[1], 0, false);
        p1 = __builtin_amdgcn_cvt_pk_fp8_f32(v1[2], v1[3], p1, true);
        i32x2 pp; pp[0] = p0; pp[1] = p1;
        *(i32x2*)(xf8 + i8) = pp;
    } else {
        __shared__ int sHistB[64], sScanB[64], sCurB[64], sBaseB[64];
        __shared__ unsigned sStage[2048];
        __shared__ u8 sBinOf[2048];
        int tid = threadIdx.x;
        int hb = b - 32 - splitB;
        long e8 = (long)hb * 2048 + tid * 8;
        bool val = e8 < N_EDGES;       // N_EDGES % 8 == 0: all-or-nothing per thread
        if (tid < 64) sHistB[tid] = 0;
        __syncthreads();
        unsigned ent[8]; int bin[8];
        if (val) {
            i32x4 d0 = *(const i32x4*)(edst + e8);
            i32x4 d1 = *(const i32x4*)(edst + e8 + 4);
            i32x4 s0 = *(const i32x4*)(esrc + e8);
            i32x4 s1 = *(const i32x4*)(esrc + e8 + 4);
            #pragma unroll
            for (int j = 0; j < 4; ++j) {
                unsigned dd = (unsigned)d0[j];
                int bi = (int)(dd / 800u);
                bin[j] = bi;
                ent[j] = ((unsigned)s0[j] << 10) | (dd - (unsigned)bi * 800u);
                dd = (unsigned)d1[j];
                bi = (int)(dd / 800u);
                bin[4 + j] = bi;
                ent[4 + j] = ((unsigned)s1[j] << 10) | (dd - (unsigned)bi * 800u);
            }
            #pragma unroll
            for (int j = 0; j < 8; ++j) atomicAdd(&sHistB[bin[j]], 1);
        }
        __syncthreads();
        if (tid < 64) {                  // wave 0: parallel 64-bin exclusive scan
            int v = sHistB[tid];
            int sc = v;
            #pragma unroll
            for (int o = 1; o < 64; o <<= 1) {
                int t = __shfl_up(sc, o);
                if (tid >= o) sc += t;
            }
            sScanB[tid] = sc - v;
            sCurB[tid] = sc - v;
            // reserve segment space now; latency hides under the scatter below
            sBaseB[tid] = v ? atomicAdd(&segCnt[tid << 4], v) : 0;
        }
        __syncthreads();
        if (val) {
            #pragma unroll
            for (int j = 0; j < 8; ++j) {
                int p = atomicAdd(&sCurB[bin[j]], 1);
                sStage[p] = ent[j];
                sBinOf[p] = (u8)bin[j];
            }
        }
        __syncthreads();
        int tcount = sScanB[63] + sHistB[63];
        for (int p = tid; p < tcount; p += 256) {
            int bn = sBinOf[p];
            long ofs = (long)sBaseB[bn] + (p - sScanB[bn]);
            if (ofs < SEGCAP)
                segBuf[(long)bn * SEGCAP + ofs] = sStage[p];
        }
    }
}

// ---------------- per-superkey counting sort -> col_srt (group-CAP layout) + hdr ----
__global__ __launch_bounds__(512) void k_sort(
        const int* __restrict__ segCnt, const unsigned* __restrict__ segBuf,
        u16* __restrict__ col_srt, u16* __restrict__ hdr) {
    __shared__ int sHist[SUPN], sStart[SUPN], sCur[SUPN];
    int tid = threadIdx.x;
    int s = blockIdx.x;
    int nnodes = N_NODES - s * SUPN; if (nnodes > SUPN) nnodes = SUPN;
    int ngroups = nnodes >> 4;
    int n = segCnt[s << 4]; if (n > SEGCAP) n = SEGCAP;
    for (int i = tid; i < SUPN; i += 512) { sHist[i] = 0; sCur[i] = 0; }
    __syncthreads();
    const unsigned* seg = segBuf + (long)s * SEGCAP;
    unsigned ent[32];
    #pragma unroll
    for (int i = 0; i < 32; ++i) {
        int idx = i * 512 + tid;                 // coalesced
        ent[i] = (idx < n) ? seg[idx] : 0xFFFFFFFFu;
    }
    #pragma unroll
    for (int i = 0; i < 32; ++i)
        if (ent[i] != 0xFFFFFFFFu) atomicAdd(&sHist[ent[i] & 1023u], 1);
    __syncthreads();
    if (tid < ngroups) {
        int base = 0;
        int gb = (s * 50 + tid) * 32;
        #pragma unroll
        for (int i = 0; i < 16; ++i) {
            int node = tid * 16 + i;
            int d = sHist[node];
            int st_c = base < CAP ? base : CAP;
            int en_c = base + d < CAP ? base + d : CAP;
            sStart[node] = base;
            hdr[gb + i] = (u16)st_c;
            hdr[gb + 16 + i] = (u16)(en_c - st_c);
            base += d;
        }
    }
    __syncthreads();
    #pragma unroll
    for (int i = 0; i < 32; ++i) {
        unsigned e = ent[i];
        if (e != 0xFFFFFFFFu) {
            int node = (int)(e & 1023u);
            int pos = atomicAdd(&sCur[node], 1);
            int ofs = sStart[node] + pos;
            if (ofs < CAP)
                col_srt[(long)(s * 50 + (node >> 4)) * CAP + ofs] = (u16)(e >> 10);
        }
    }
}

// decode 16 fp8 + accumulate — packed f32x2 path (v_pk_add_f32)
__device__ __forceinline__ void acc_row16(u32x4 w, f32x2 sum2[8]) {
    #pragma unroll
    for (int h = 0; h < 4; ++h) {
        sum2[2 * h]     += __builtin_amdgcn_cvt_pk_f32_fp8((int)w[h], false);
        sum2[2 * h + 1] += __builtin_amdgcn_cvt_pk_f32_fp8((int)w[h], true);
    }
}

// ---------------- fused AGG + GEMM + BN-stats (256 threads; proven round-8 shape) ----
// Both stages use this identical kernel: gather fp8 fq, root bf16 fh.
__global__ __launch_bounds__(256) void k_ag(
        const u8* __restrict__ fq, const u16* __restrict__ fh,
        const u16* __restrict__ hdr, const u16* __restrict__ col_srt,
        const u16* __restrict__ Bph, const float* __restrict__ bias,
        u16* __restrict__ h16, float* __restrict__ stats) {
    __shared__ u16 sA[16 * SROW];
    __shared__ __align__(16) u16 sIdx[CAP];
    int tid = threadIdx.x;
    long nodebase = (long)blockIdx.x * 16;       // 3125*16 == 50000 exact

    // stage sorted index list (1KB) into LDS
    if (tid < 64)
        *(us8*)(sIdx + tid * 8) = *(const us8*)(col_srt + (long)blockIdx.x * CAP + tid * 8);
    __syncthreads();

    // ---- phase 1: gather-mean (fp8, 16B/lane, even/odd edge split) ----
    {
        int grp = tid >> 4;          // node 0..15
        int g   = tid & 15;
        int sub = g >> 3;            // 0: even edges, 1: odd edges
        int gl  = g & 7;
        int d16 = gl * 16;           // dim base
        int st  = hdr[blockIdx.x * 32 + grp];
        int deg = hdr[blockIdx.x * 32 + 16 + grp];
        int s = st, e = st + deg;
        f32x2 sum2[8];
        #pragma unroll
        for (int p = 0; p < 8; ++p) sum2[p] = (f32x2){0.f, 0.f};
        int j = s + sub;
        for (; j + 6 < e; j += 8) {          // 4 loads in flight
            int i0 = sIdx[j], i1 = sIdx[j + 2], i2 = sIdx[j + 4], i3 = sIdx[j + 6];
            u32x4 w0 = *(const u32x4*)(fq + (long)i0 * DIM + d16);
            u32x4 w1 = *(const u32x4*)(fq + (long)i1 * DIM + d16);
            u32x4 w2 = *(const u32x4*)(fq + (long)i2 * DIM + d16);
            u32x4 w3 = *(const u32x4*)(fq + (long)i3 * DIM + d16);
            acc_row16(w0, sum2);
            acc_row16(w1, sum2);
            acc_row16(w2, sum2);
            acc_row16(w3, sum2);
        }
        for (; j < e; j += 2) {
            int i0 = sIdx[j];
            u32x4 w0 = *(const u32x4*)(fq + (long)i0 * DIM + d16);
            acc_row16(w0, sum2);
        }
        // combine even/odd halves (once per node)
        #pragma unroll
        for (int p = 0; p < 8; ++p) {
            sum2[p][0] += __shfl_xor(sum2[p][0], 8);
            sum2[p][1] += __shfl_xor(sum2[p][1], 8);
        }
        if (sub == 0) {
            float dn = (deg > 0) ? 1.f / (float)deg : 1.f;
            us8 r0, r1;
            #pragma unroll
            for (int k = 0; k < 8; ++k) {
                r0[k] = f2bf(sum2[k >> 1][k & 1] * dn);          // dims d16+0..7
                r1[k] = f2bf(sum2[4 + (k >> 1)][k & 1] * dn);    // dims d16+8..15
            }
            *(us8*)(sA + grp * SROW + d16) = r0;
            *(us8*)(sA + grp * SROW + d16 + 8) = r1;
        }
    }
    __syncthreads();

    // ---- phase 2: MFMA ----
    int cg = tid >> 6, lane = tid & 63;
    int q = lane >> 4, nn = lane & 15;
    long rc = nodebase + nn;

    short8 ah[8];
    #pragma unroll
    for (int kc = 0; kc < 4; ++kc)
        ah[kc] = *(const short8*)(sA + nn * SROW + kc * 32 + q * 8);
    #pragma unroll
    for (int kc = 0; kc < 4; ++kc) {
        int ko = kc * 32 + q * 8;
        us8 rv = *(const us8*)(fh + rc * DIM + ko);
        short8 t;
        #pragma unroll
        for (int j = 0; j < 8; ++j) t[j] = (short)rv[j];
        ah[4 + kc] = t;
    }

    f32x4 acc[2];
    acc[0] = (f32x4){0.f, 0.f, 0.f, 0.f};
    acc[1] = (f32x4){0.f, 0.f, 0.f, 0.f};

    #pragma unroll
    for (int kc = 0; kc < 8; ++kc) {
        #pragma unroll
        for (int nt = 0; nt < 2; ++nt) {
            int ntg = cg * 2 + nt;
            short8 bh = *(const short8*)(Bph + (((ntg * 8 + kc) * 64 + lane) << 3));
            acc[nt] = __builtin_amdgcn_mfma_f32_16x16x32_bf16(ah[kc], bh, acc[nt], 0, 0, 0);
        }
    }

    int bank = blockIdx.x & 7;
    #pragma unroll
    for (int nt = 0; nt < 2; ++nt) {
        int col = cg * 32 + nt * 16 + nn;
        float bv = bias[col];
        float ps = 0.f, pq = 0.f;
        #pragma unroll
        for (int r = 0; r < 4; ++r) {
            float v = acc[nt][r] + bv;
            long idx = (nodebase + q * 4 + r) * DIM + col;
            h16[idx] = f2bf(v);
            ps += v; pq += v * v;
        }
        ps += __shfl_xor(ps, 16);
        ps += __shfl_xor(ps, 32);
        pq += __shfl_xor(pq, 16);
        pq += __shfl_xor(pq, 32);
        if (q == 0) {
            atomicAdd(&stats[bank * 512 + col], ps);
            atomicAdd(&stats[bank * 512 + 256 + col], pq);
        }
    }
}

// ---------------- h_act = relu(bn1(h1)) once per node -> bf16 (root) + fp8 (gather) ----
__global__ __launch_bounds__(256) void k_act(
        const u16* __restrict__ h, const float* __restrict__ stats,
        const float* __restrict__ g, const float* __restrict__ bt,
        u16* __restrict__ outh, u8* __restrict__ outq) {
    __shared__ float acS[256];
    int tid = threadIdx.x;
    if (tid < 128) {
        float s = 0.f, qq = 0.f;
        #pragma unroll
        for (int b = 0; b < 8; ++b) {
            s  += stats[b * 512 + tid];
            qq += stats[b * 512 + 256 + tid];
        }
        float mu = s * NINV;
        float var = qq * NINV - mu * mu;
        float a = g[tid] * rsqrtf(var + 1e-5f);
        acS[tid] = a;
        acS[128 + tid] = bt[tid] - mu * a;
    }
    __syncthreads();
    long i8 = ((long)blockIdx.x * 256 + tid) * 8;
    int c = (int)(i8 & 127);
    us8 hv = *(const us8*)(h + i8);
    us8 r;
    float v[8];
    #pragma unroll
    for (int j = 0; j < 8; ++j) {
        float t = bf2f(hv[j]) * acS[c + j] + acS[128 + c + j];
        t = t > 0.f ? t : 0.f;
        v[j] = t;
        r[j] = f2bf(t);
    }
    *(us8*)(outh + i8) = r;
    int p0 = __builtin_amdgcn_cvt_pk_fp8_f32(v[0], v[1], 0, false);
    p0 = __builtin_amdgcn_cvt_pk_fp8_f32(v[2], v[3], p0, true);
    int p1 = __builtin_amdgcn_cvt_pk_fp8_f32(v[4], v[5], 0, false);
    p1 = __builtin_amdgcn_cvt_pk_fp8_f32(v[6], v[7], p1, true);
    i32x2 pp; pp[0] = p0; pp[1] = p1;
    *(i32x2*)(outq + i8) = pp;
}

// out = relu(bn(h)+x); coeffs computed in-block from banked stats
__global__ __launch_bounds__(256) void k_bn_add_relu(
        const u16* __restrict__ h, const float* __restrict__ stats,
        const float* __restrict__ g, const float* __restrict__ bt,
        const float* __restrict__ x, float* __restrict__ outv) {
    __shared__ float acS[256];
    int tid = threadIdx.x;
    if (tid < 128) {
        float s = 0.f, qq = 0.f;
        #pragma unroll
        for (int b = 0; b < 8; ++b) {
            s  += stats[b * 512 + tid];
            qq += stats[b * 512 + 256 + tid];
        }
        float mu = s * NINV;
        float var = qq * NINV - mu * mu;
        float a = g[tid] * rsqrtf(var + 1e-5f);
        acS[tid] = a;
        acS[128 + tid] = bt[tid] - mu * a;
    }
    __syncthreads();
    long i8 = ((long)blockIdx.x * 256 + tid) * 8;
    int c = (int)(i8 & 127);
    us8 hv = *(const us8*)(h + i8);
    f32x4 x0 = *(const f32x4*)(x + i8);
    f32x4 x1 = *(const f32x4*)(x + i8 + 4);
    f32x4 r0, r1;
    #pragma unroll
    for (int j = 0; j < 4; ++j) {
        float v = bf2f(hv[j]) * acS[c + j] + acS[128 + c + j] + x0[j];
        r0[j] = v > 0.f ? v : 0.f;
        float w = bf2f(hv[4 + j]) * acS[c + 4 + j] + acS[128 + c + 4 + j] + x1[j];
        r1[j] = w > 0.f ? w : 0.f;
    }
    *(f32x4*)(outv + i8) = r0;
    *(f32x4*)(outv + i8 + 4) = r1;
}

extern "C" void kernel_launch(void* const* d_in, const int* in_sizes, int n_in,
                              void* d_out, int out_size, void* d_ws, size_t ws_size,
                              hipStream_t stream) {
    (void)in_sizes; (void)n_in; (void)out_size; (void)ws_size;
    const float* x   = (const float*)d_in[0];
    const int*   ei  = (const int*)d_in[1];
    const float* W1l = (const float*)d_in[2];
    const float* b1  = (const float*)d_in[3];
    const float* W1r = (const float*)d_in[4];
    const float* g1  = (const float*)d_in[5];
    const float* bt1 = (const float*)d_in[6];
    const float* W2l = (const float*)d_in[7];
    const float* b2  = (const float*)d_in[8];
    const float* W2r = (const float*)d_in[9];
    const float* g2  = (const float*)d_in[10];
    const float* bt2 = (const float*)d_in[11];
    float* out = (float*)d_out;

    const int* esrc = ei;
    const int* edst = ei + N_EDGES;

    char* ws = (char*)d_ws;
    size_t off = 0;
    auto alloc = [&](size_t bytes) { size_t p = off; off = (off + bytes + 255) & ~(size_t)255; return p; };
    float* stats1  = (float*)(ws + alloc(4096 * 4));   // 8 banks x 512 (sum@+col, sumsq@+256+col)
    float* stats2  = (float*)(ws + alloc(4096 * 4));
    int*   segCnt  = (int*)  (ws + alloc(64 * 16 * 4));   // 1 counter per 64B line
    size_t zero_bytes = off;                       // everything above must be zeroed
    unsigned* segBuf = (unsigned*)(ws + alloc((size_t)NSUP * SEGCAP * 4));
    u16*   col_srt = (u16*)  (ws + alloc((size_t)NBKT * CAP * 2));
    u16*   hdr     = (u16*)  (ws + alloc((size_t)NBKT * 32 * 2));
    u16*   xh      = (u16*)  (ws + alloc((size_t)N_NODES * DIM * 2));
    u8*    xf8     = (u8*)   (ws + alloc((size_t)N_NODES * DIM));
    u16*   hb1     = (u16*)  (ws + alloc((size_t)N_NODES * DIM * 2));  // raw h1 bf16
    u16*   hah     = (u16*)  (ws + alloc((size_t)N_NODES * DIM * 2));  // h_act bf16
    u8*    haf8    = (u8*)   (ws + alloc((size_t)N_NODES * DIM));     // h_act fp8
    u16*   hb2     = (u16*)  (ws + alloc((size_t)N_NODES * DIM * 2));  // raw h2 bf16
    u16*   Bp1h    = (u16*)  (ws + alloc(256 * 128 * 2));
    u16*   Bp2h    = (u16*)  (ws + alloc(256 * 128 * 2));

    hipMemsetAsync(ws, 0, zero_bytes, stream);

    const int AGB = N_NODES / 16;                    // 3125 exact
    const int EWB8 = (int)(((long)N_NODES * DIM) / 2048);  // 3125 exact (8 f32/thread)
    const int EDGB = (N_EDGES + 2047) / 2048;        // 391 (8 edges/thread)
    const int PREPB = 32 + EWB8 + EDGB;              // pack + split + binned append

    // prep: pack both B + split x (bf16 + fp8) + LDS-binned segmented bucketing
    k_prep<<<PREPB, 256, 0, stream>>>(W1l, W1r, Bp1h, W2l, W2r, Bp2h, x, xh, xf8,
                                      esrc, edst, segCnt, segBuf, EWB8);

    // per-superkey counting sort -> col_srt (group-CAP layout) + hdr
    k_sort<<<NSUP, 512, 0, stream>>>(segCnt, segBuf, col_srt, hdr);

    // stage 1: fused agg+gemm on x (fp8 gather, bf16 root); writes h1 bf16 + stats1
    k_ag<<<AGB, 256, 0, stream>>>(xf8, xh, hdr, col_srt, Bp1h, b1, hb1, stats1);

    // h_act = relu(bn1(h1)) once per node -> bf16 + fp8
    k_act<<<EWB8, 256, 0, stream>>>(hb1, stats1, g1, bt1, hah, haf8);

    // stage 2: fused agg+gemm on h_act; writes h2 bf16 + stats2
    k_ag<<<AGB, 256, 0, stream>>>(haf8, hah, hdr, col_srt, Bp2h, b2, hb2, stats2);

    // epilogue: out = relu(bn(h2) + x), coeffs from stats2
    k_bn_add_relu<<<EWB8, 256, 0, stream>>>(hb2, stats2, g2, bt2, x, out);
}

// Round 12
// 192.806 us; speedup vs baseline: 1.1718x; 1.0324x over previous
//
#include <hip/hip_runtime.h>

typedef unsigned short u16;
typedef unsigned char u8;
typedef __attribute__((ext_vector_type(8))) short short8;
typedef __attribute__((ext_vector_type(2))) float f32x2;
typedef __attribute__((ext_vector_type(4))) float f32x4;
typedef __attribute__((ext_vector_type(4))) int i32x4;
typedef __attribute__((ext_vector_type(2))) int i32x2;
typedef __attribute__((ext_vector_type(4))) unsigned short us4;
typedef __attribute__((ext_vector_type(8))) unsigned short us8;
typedef __attribute__((ext_vector_type(4))) unsigned int u32x4;

#define N_NODES 50000
#define N_EDGES 800000
#define DIM 128
#define NINV (1.0f / 50000.0f)
#define SROW 136      /* LDS row stride (u16) */
#define NBKT 3125     /* node groups of 16: 50000/16 */
#define CAP 512       /* per-group capacity; mean 256, P(overflow) ~ e^-99 */
#define SUPN 256      /* nodes per superkey (16 groups); bin = dst>>8, local = dst&255 */
#define NSUP 196      /* ceil(50000/256); last superkey has 80 nodes (5 groups) */
#define SEGCAP 5120   /* segment entries per superkey; mean 4096, +16 sigma margin */

__device__ __forceinline__ float bf2f(u16 u) {
    union { unsigned int i; float f; } v; v.i = ((unsigned int)u) << 16; return v.f;
}
__device__ __forceinline__ u16 f2bf(float f) {
    union { float f; unsigned int i; } v; v.f = f;
    return (u16)((v.i + 0x7FFFu + ((v.i >> 16) & 1u)) >> 16);
}

// ---------------- prep: pack B1/B2, split x, LDS-binned segmented edge bucketing ----
// blocks 0..15: pack B1; 16..31: pack B2; 32..32+splitB-1: split x (8 floats/thread);
// rest (391): 2048 edges/block (8/thread). LDS-bin into 196 superkeys (bin = dst>>8,
// shift not divide) with a 4-wave shfl scan; ONE segment-reserve global atomic per
// non-empty (block, superkey), reserve latency hidden under LDS scatter; coalesced
// run-writes into per-superkey segments. Entry = src<<8 | (dst & 255).
__global__ __launch_bounds__(256) void k_prep(
        const float* __restrict__ W1l, const float* __restrict__ W1r, u16* __restrict__ Bp1,
        const float* __restrict__ W2l, const float* __restrict__ W2r, u16* __restrict__ Bp2,
        const float* __restrict__ x, u16* __restrict__ xh, u8* __restrict__ xf8,
        const int* __restrict__ esrc, const int* __restrict__ edst,
        int* __restrict__ segCnt, unsigned* __restrict__ segBuf, int splitB) {
    int b = blockIdx.x;
    if (b < 32) {
        const float* Wl = (b < 16) ? W1l : W2l;
        const float* Wr = (b < 16) ? W1r : W2r;
        u16* Bp = (b < 16) ? Bp1 : Bp2;
        int idx = (b & 15) * 256 + threadIdx.x;      // 0..4095
        int lane = idx & 63;
        int kc = (idx >> 6) & 7;
        int nt = idx >> 9;
        int q = lane >> 4, nn = lane & 15;
        int col = nt * 16 + nn;
        #pragma unroll
        for (int j = 0; j < 8; ++j) {
            int k = kc * 32 + q * 8 + j;
            float v = (k < 128) ? Wl[k * 128 + col] : Wr[(k - 128) * 128 + col];
            Bp[(long)idx * 8 + j] = f2bf(v);
        }
    } else if (b < 32 + splitB) {
        long i8 = ((long)(b - 32) * 256 + threadIdx.x) * 8;
        f32x4 v0 = *(const f32x4*)(x + i8);
        f32x4 v1 = *(const f32x4*)(x + i8 + 4);
        us8 h;
        #pragma unroll
        for (int j = 0; j < 4; ++j) { h[j] = f2bf(v0[j]); h[4 + j] = f2bf(v1[j]); }
        *(us8*)(xh + i8) = h;
        int p0 = __builtin_amdgcn_cvt_pk_fp8_f32(v0[0], v0[1], 0, false);
        p0 = __builtin_amdgcn_cvt_pk_fp8_f32(v0[2], v0[3], p0, true);
        int p1 = __builtin_amdgcn_cvt_pk_fp8_f32(v1[0], v1[1], 0, false);
        p1 = __builtin_amdgcn_cvt_pk_fp8_f32(v1[2], v1[3], p1, true);
        i32x2 pp; pp[0] = p0; pp[1] = p1;
        *(i32x2*)(xf8 + i8) = pp;
    } else {
        __shared__ int sHistB[256], sScanB[256], sCurB[256], sBaseB[256];
        __shared__ int sWaveSum[4];
        __shared__ unsigned sStage[2048];
        __shared__ u8 sBinOf[2048];
        int tid = threadIdx.x;
        int hb = b - 32 - splitB;
        long e8 = (long)hb * 2048 + tid * 8;
        bool val = e8 < N_EDGES;       // N_EDGES % 8 == 0: all-or-nothing per thread
        sHistB[tid] = 0;
        __syncthreads();
        unsigned ent[8]; int bin[8];
        if (val) {
            i32x4 d0 = *(const i32x4*)(edst + e8);
            i32x4 d1 = *(const i32x4*)(edst + e8 + 4);
            i32x4 s0 = *(const i32x4*)(esrc + e8);
            i32x4 s1 = *(const i32x4*)(esrc + e8 + 4);
            #pragma unroll
            for (int j = 0; j < 4; ++j) {
                unsigned dd = (unsigned)d0[j];
                bin[j] = (int)(dd >> 8);
                ent[j] = ((unsigned)s0[j] << 8) | (dd & 255u);
                dd = (unsigned)d1[j];
                bin[4 + j] = (int)(dd >> 8);
                ent[4 + j] = ((unsigned)s1[j] << 8) | (dd & 255u);
            }
            #pragma unroll
            for (int j = 0; j < 8; ++j) atomicAdd(&sHistB[bin[j]], 1);
        }
        __syncthreads();
        // 4-wave parallel exclusive scan over 196 bins + cross-wave offsets
        int w = tid >> 6, lane = tid & 63;
        int v = (tid < NSUP) ? sHistB[tid] : 0;
        int sc = v;
        #pragma unroll
        for (int o = 1; o < 64; o <<= 1) {
            int t = __shfl_up(sc, o);
            if (lane >= o) sc += t;
        }
        if (lane == 63) sWaveSum[w] = sc;
        __syncthreads();
        if (tid == 0) {
            int acc = 0;
            #pragma unroll
            for (int i = 0; i < 4; ++i) { int t = sWaveSum[i]; sWaveSum[i] = acc; acc += t; }
        }
        __syncthreads();
        if (tid < NSUP) {
            int excl = sc - v + sWaveSum[w];
            sScanB[tid] = excl;
            sCurB[tid] = excl;
            // reserve segment space now; latency hides under the scatter below
            sBaseB[tid] = v ? atomicAdd(&segCnt[tid << 4], v) : 0;
        }
        __syncthreads();
        if (val) {
            #pragma unroll
            for (int j = 0; j < 8; ++j) {
                int p = atomicAdd(&sCurB[bin[j]], 1);
                sStage[p] = ent[j];
                sBinOf[p] = (u8)bin[j];
            }
        }
        __syncthreads();
        int tcount = sScanB[NSUP - 1] + sHistB[NSUP - 1];
        for (int p = tid; p < tcount; p += 256) {
            int bn = sBinOf[p];
            long ofs = (long)sBaseB[bn] + (p - sScanB[bn]);
            if (ofs < SEGCAP)
                segBuf[(long)bn * SEGCAP + ofs] = sStage[p];
        }
    }
}

// ---------------- per-superkey counting sort -> col_srt (group-CAP layout) + hdr ----
// 196 blocks x 512 threads (~1 block/CU on 3/4 of the chip); 10 entries/thread.
__global__ __launch_bounds__(512) void k_sort(
        const int* __restrict__ segCnt, const unsigned* __restrict__ segBuf,
        u16* __restrict__ col_srt, u16* __restrict__ hdr) {
    __shared__ int sHist[SUPN], sStart[SUPN], sCur[SUPN];
    int tid = threadIdx.x;
    int s = blockIdx.x;
    int nnodes = N_NODES - s * SUPN; if (nnodes > SUPN) nnodes = SUPN;
    int ngroups = nnodes >> 4;           // 16, or 5 for the last superkey
    int n = segCnt[s << 4]; if (n > SEGCAP) n = SEGCAP;
    if (tid < SUPN) { sHist[tid] = 0; sCur[tid] = 0; }
    __syncthreads();
    const unsigned* seg = segBuf + (long)s * SEGCAP;
    unsigned ent[10];
    #pragma unroll
    for (int i = 0; i < 10; ++i) {
        int idx = i * 512 + tid;                 // coalesced
        ent[i] = (idx < n) ? seg[idx] : 0xFFFFFFFFu;
    }
    #pragma unroll
    for (int i = 0; i < 10; ++i)
        if (ent[i] != 0xFFFFFFFFu) atomicAdd(&sHist[ent[i] & 255u], 1);
    __syncthreads();
    if (tid < ngroups) {
        int base = 0;
        int gb = (s * 16 + tid) * 32;
        #pragma unroll
        for (int i = 0; i < 16; ++i) {
            int node = tid * 16 + i;
            int d = sHist[node];
            int st_c = base < CAP ? base : CAP;
            int en_c = base + d < CAP ? base + d : CAP;
            sStart[node] = base;
            hdr[gb + i] = (u16)st_c;
            hdr[gb + 16 + i] = (u16)(en_c - st_c);
            base += d;
        }
    }
    __syncthreads();
    #pragma unroll
    for (int i = 0; i < 10; ++i) {
        unsigned e = ent[i];
        if (e != 0xFFFFFFFFu) {
            int node = (int)(e & 255u);
            int pos = atomicAdd(&sCur[node], 1);
            int ofs = sStart[node] + pos;
            if (ofs < CAP)
                col_srt[(long)(s * 16 + (node >> 4)) * CAP + ofs] = (u16)(e >> 8);
        }
    }
}

// decode 16 fp8 + accumulate — packed f32x2 path (v_pk_add_f32)
__device__ __forceinline__ void acc_row16(u32x4 w, f32x2 sum2[8]) {
    #pragma unroll
    for (int h = 0; h < 4; ++h) {
        sum2[2 * h]     += __builtin_amdgcn_cvt_pk_f32_fp8((int)w[h], false);
        sum2[2 * h + 1] += __builtin_amdgcn_cvt_pk_f32_fp8((int)w[h], true);
    }
}

// ---------------- fused AGG + GEMM + BN-stats (256 threads; proven round-8 shape) ----
// Both stages use this identical kernel: gather fp8 fq, root bf16 fh.
__global__ __launch_bounds__(256) void k_ag(
        const u8* __restrict__ fq, const u16* __restrict__ fh,
        const u16* __restrict__ hdr, const u16* __restrict__ col_srt,
        const u16* __restrict__ Bph, const float* __restrict__ bias,
        u16* __restrict__ h16, float* __restrict__ stats) {
    __shared__ u16 sA[16 * SROW];
    __shared__ __align__(16) u16 sIdx[CAP];
    int tid = threadIdx.x;
    long nodebase = (long)blockIdx.x * 16;       // 3125*16 == 50000 exact

    // stage sorted index list (1KB) into LDS
    if (tid < 64)
        *(us8*)(sIdx + tid * 8) = *(const us8*)(col_srt + (long)blockIdx.x * CAP + tid * 8);
    __syncthreads();

    // ---- phase 1: gather-mean (fp8, 16B/lane, even/odd edge split) ----
    {
        int grp = tid >> 4;          // node 0..15
        int g   = tid & 15;
        int sub = g >> 3;            // 0: even edges, 1: odd edges
        int gl  = g & 7;
        int d16 = gl * 16;           // dim base
        int st  = hdr[blockIdx.x * 32 + grp];
        int deg = hdr[blockIdx.x * 32 + 16 + grp];
        int s = st, e = st + deg;
        f32x2 sum2[8];
        #pragma unroll
        for (int p = 0; p < 8; ++p) sum2[p] = (f32x2){0.f, 0.f};
        int j = s + sub;
        for (; j + 6 < e; j += 8) {          // 4 loads in flight
            int i0 = sIdx[j], i1 = sIdx[j + 2], i2 = sIdx[j + 4], i3 = sIdx[j + 6];
            u32x4 w0 = *(const u32x4*)(fq + (long)i0 * DIM + d16);
            u32x4 w1 = *(const u32x4*)(fq + (long)i1 * DIM + d16);
            u32x4 w2 = *(const u32x4*)(fq + (long)i2 * DIM + d16);
            u32x4 w3 = *(const u32x4*)(fq + (long)i3 * DIM + d16);
            acc_row16(w0, sum2);
            acc_row16(w1, sum2);
            acc_row16(w2, sum2);
            acc_row16(w3, sum2);
        }
        for (; j < e; j += 2) {
            int i0 = sIdx[j];
            u32x4 w0 = *(const u32x4*)(fq + (long)i0 * DIM + d16);
            acc_row16(w0, sum2);
        }
        // combine even/odd halves (once per node)
        #pragma unroll
        for (int p = 0; p < 8; ++p) {
            sum2[p][0] += __shfl_xor(sum2[p][0], 8);
            sum2[p][1] += __shfl_xor(sum2[p][1], 8);
        }
        if (sub == 0) {
            float dn = (deg > 0) ? 1.f / (float)deg : 1.f;
            us8 r0, r1;
            #pragma unroll
            for (int k = 0; k < 8; ++k) {
                r0[k] = f2bf(sum2[k >> 1][k & 1] * dn);          // dims d16+0..7
                r1[k] = f2bf(sum2[4 + (k >> 1)][k & 1] * dn);    // dims d16+8..15
            }
            *(us8*)(sA + grp * SROW + d16) = r0;
            *(us8*)(sA + grp * SROW + d16 + 8) = r1;
        }
    }
    __syncthreads();

    // ---- phase 2: MFMA ----
    int cg = tid >> 6, lane = tid & 63;
    int q = lane >> 4, nn = lane & 15;
    long rc = nodebase + nn;

    short8 ah[8];
    #pragma unroll
    for (int kc = 0; kc < 4; ++kc)
        ah[kc] = *(const short8*)(sA + nn * SROW + kc * 32 + q * 8);
    #pragma unroll
    for (int kc = 0; kc < 4; ++kc) {
        int ko = kc * 32 + q * 8;
        us8 rv = *(const us8*)(fh + rc * DIM + ko);
        short8 t;
        #pragma unroll
        for (int j = 0; j < 8; ++j) t[j] = (short)rv[j];
        ah[4 + kc] = t;
    }

    f32x4 acc[2];
    acc[0] = (f32x4){0.f, 0.f, 0.f, 0.f};
    acc[1] = (f32x4){0.f, 0.f, 0.f, 0.f};

    #pragma unroll
    for (int kc = 0; kc < 8; ++kc) {
        #pragma unroll
        for (int nt = 0; nt < 2; ++nt) {
            int ntg = cg * 2 + nt;
            short8 bh = *(const short8*)(Bph + (((ntg * 8 + kc) * 64 + lane) << 3));
            acc[nt] = __builtin_amdgcn_mfma_f32_16x16x32_bf16(ah[kc], bh, acc[nt], 0, 0, 0);
        }
    }

    int bank = blockIdx.x & 7;
    #pragma unroll
    for (int nt = 0; nt < 2; ++nt) {
        int col = cg * 32 + nt * 16 + nn;
        float bv = bias[col];
        float ps = 0.f, pq = 0.f;
        #pragma unroll
        for (int r = 0; r < 4; ++r) {
            float v = acc[nt][r] + bv;
            long idx = (nodebase + q * 4 + r) * DIM + col;
            h16[idx] = f2bf(v);
            ps += v; pq += v * v;
        }
        ps += __shfl_xor(ps, 16);
        ps += __shfl_xor(ps, 32);
        pq += __shfl_xor(pq, 16);
        pq += __shfl_xor(pq, 32);
        if (q == 0) {
            atomicAdd(&stats[bank * 512 + col], ps);
            atomicAdd(&stats[bank * 512 + 256 + col], pq);
        }
    }
}

// ---------------- h_act = relu(bn1(h1)) once per node -> bf16 (root) + fp8 (gather) ----
__global__ __launch_bounds__(256) void k_act(
        const u16* __restrict__ h, const float* __restrict__ stats,
        const float* __restrict__ g, const float* __restrict__ bt,
        u16* __restrict__ outh, u8* __restrict__ outq) {
    __shared__ float acS[256];
    int tid = threadIdx.x;
    if (tid < 128) {
        float s = 0.f, qq = 0.f;
        #pragma unroll
        for (int b = 0; b < 8; ++b) {
            s  += stats[b * 512 + tid];
            qq += stats[b * 512 + 256 + tid];
        }
        float mu = s * NINV;
        float var = qq * NINV - mu * mu;
        float a = g[tid] * rsqrtf(var + 1e-5f);
        acS[tid] = a;
        acS[128 + tid] = bt[tid] - mu * a;
    }
    __syncthreads();
    long i8 = ((long)blockIdx.x * 256 + tid) * 8;
    int c = (int)(i8 & 127);
    us8 hv = *(const us8*)(h + i8);
    us8 r;
    float v[8];
    #pragma unroll
    for (int j = 0; j < 8; ++j) {
        float t = bf2f(hv[j]) * acS[c + j] + acS[128 + c + j];
        t = t > 0.f ? t : 0.f;
        v[j] = t;
        r[j] = f2bf(t);
    }
    *(us8*)(outh + i8) = r;
    int p0 = __builtin_amdgcn_cvt_pk_fp8_f32(v[0], v[1], 0, false);
    p0 = __builtin_amdgcn_cvt_pk_fp8_f32(v[2], v[3], p0, true);
    int p1 = __builtin_amdgcn_cvt_pk_fp8_f32(v[4], v[5], 0, false);
    p1 = __builtin_amdgcn_cvt_pk_fp8_f32(v[6], v[7], p1, true);
    i32x2 pp; pp[0] = p0; pp[1] = p1;
    *(i32x2*)(outq + i8) = pp;
}

// out = relu(bn(h)+x); coeffs computed in-block from banked stats
__global__ __launch_bounds__(256) void k_bn_add_relu(
        const u16* __restrict__ h, const float* __restrict__ stats,
        const float* __restrict__ g, const float* __restrict__ bt,
        const float* __restrict__ x, float* __restrict__ outv) {
    __shared__ float acS[256];
    int tid = threadIdx.x;
    if (tid < 128) {
        float s = 0.f, qq = 0.f;
        #pragma unroll
        for (int b = 0; b < 8; ++b) {
            s  += stats[b * 512 + tid];
            qq += stats[b * 512 + 256 + tid];
        }
        float mu = s * NINV;
        float var = qq * NINV - mu * mu;
        float a = g[tid] * rsqrtf(var + 1e-5f);
        acS[tid] = a;
        acS[128 + tid] = bt[tid] - mu * a;
    }
    __syncthreads();
    long i8 = ((long)blockIdx.x * 256 + tid) * 8;
    int c = (int)(i8 & 127);
    us8 hv = *(const us8*)(h + i8);
    f32x4 x0 = *(const f32x4*)(x + i8);
    f32x4 x1 = *(const f32x4*)(x + i8 + 4);
    f32x4 r0, r1;
    #pragma unroll
    for (int j = 0; j < 4; ++j) {
        float v = bf2f(hv[j]) * acS[c + j] + acS[128 + c + j] + x0[j];
        r0[j] = v > 0.f ? v : 0.f;
        float w = bf2f(hv[4 + j]) * acS[c + 4 + j] + acS[128 + c + 4 + j] + x1[j];
        r1[j] = w > 0.f ? w : 0.f;
    }
    *(f32x4*)(outv + i8) = r0;
    *(f32x4*)(outv + i8 + 4) = r1;
}

extern "C" void kernel_launch(void* const* d_in, const int* in_sizes, int n_in,
                              void* d_out, int out_size, void* d_ws, size_t ws_size,
                              hipStream_t stream) {
    (void)in_sizes; (void)n_in; (void)out_size; (void)ws_size;
    const float* x   = (const float*)d_in[0];
    const int*   ei  = (const int*)d_in[1];
    const float* W1l = (const float*)d_in[2];
    const float* b1  = (const float*)d_in[3];
    const float* W1r = (const float*)d_in[4];
    const float* g1  = (const float*)d_in[5];
    const float* bt1 = (const float*)d_in[6];
    const float* W2l = (const float*)d_in[7];
    const float* b2  = (const float*)d_in[8];
    const float* W2r = (const float*)d_in[9];
    const float* g2  = (const float*)d_in[10];
    const float* bt2 = (const float*)d_in[11];
    float* out = (float*)d_out;

    const int* esrc = ei;
    const int* edst = ei + N_EDGES;

    char* ws = (char*)d_ws;
    size_t off = 0;
    auto alloc = [&](size_t bytes) { size_t p = off; off = (off + bytes + 255) & ~(size_t)255; return p; };
    float* stats1  = (float*)(ws + alloc(4096 * 4));   // 8 banks x 512 (sum@+col, sumsq@+256+col)
    float* stats2  = (float*)(ws + alloc(4096 * 4));
    int*   segCnt  = (int*)  (ws + alloc(256 * 16 * 4));   // 1 counter per 64B line
    size_t zero_bytes = off;                       // everything above must be zeroed
    unsigned* segBuf = (unsigned*)(ws + alloc((size_t)NSUP * SEGCAP * 4));
    u16*   col_srt = (u16*)  (ws + alloc((size_t)NBKT * CAP * 2));
    u16*   hdr     = (u16*)  (ws + alloc((size_t)NBKT * 32 * 2));
    u16*   xh      = (u16*)  (ws + alloc((size_t)N_NODES * DIM * 2));
    u8*    xf8     = (u8*)   (ws + alloc((size_t)N_NODES * DIM));
    u16*   hb1     = (u16*)  (ws + alloc((size_t)N_NODES * DIM * 2));  // raw h1 bf16
    u16*   hah     = (u16*)  (ws + alloc((size_t)N_NODES * DIM * 2));  // h_act bf16
    u8*    haf8    = (u8*)   (ws + alloc((size_t)N_NODES * DIM));     // h_act fp8
    u16*   hb2     = (u16*)  (ws + alloc((size_t)N_NODES * DIM * 2));  // raw h2 bf16
    u16*   Bp1h    = (u16*)  (ws + alloc(256 * 128 * 2));
    u16*   Bp2h    = (u16*)  (ws + alloc(256 * 128 * 2));

    hipMemsetAsync(ws, 0, zero_bytes, stream);

    const int AGB = N_NODES / 16;                    // 3125 exact
    const int EWB8 = (int)(((long)N_NODES * DIM) / 2048);  // 3125 exact (8 f32/thread)
    const int EDGB = (N_EDGES + 2047) / 2048;        // 391 (8 edges/thread)
    const int PREPB = 32 + EWB8 + EDGB;              // pack + split + binned append

    // prep: pack both B + split x (bf16 + fp8) + LDS-binned segmented bucketing
    k_prep<<<PREPB, 256, 0, stream>>>(W1l, W1r, Bp1h, W2l, W2r, Bp2h, x, xh, xf8,
                                      esrc, edst, segCnt, segBuf, EWB8);

    // per-superkey counting sort -> col_srt (group-CAP layout) + hdr
    k_sort<<<NSUP, 512, 0, stream>>>(segCnt, segBuf, col_srt, hdr);

    // stage 1: fused agg+gemm on x (fp8 gather, bf16 root); writes h1 bf16 + stats1
    k_ag<<<AGB, 256, 0, stream>>>(xf8, xh, hdr, col_srt, Bp1h, b1, hb1, stats1);

    // h_act = relu(bn1(h1)) once per node -> bf16 + fp8
    k_act<<<EWB8, 256, 0, stream>>>(hb1, stats1, g1, bt1, hah, haf8);

    // stage 2: fused agg+gemm on h_act; writes h2 bf16 + stats2
    k_ag<<<AGB, 256, 0, stream>>>(haf8, hah, hdr, col_srt, Bp2h, b2, hb2, stats2);

    // epilogue: out = relu(bn(h2) + x), coeffs from stats2
    k_bn_add_relu<<<EWB8, 256, 0, stream>>>(hb2, stats2, g2, bt2, x, out);
}

// Round 13
// 192.553 us; speedup vs baseline: 1.1734x; 1.0013x over previous
//
#include <hip/hip_runtime.h>

typedef unsigned short u16;
typedef unsigned char u8;
typedef __attribute__((ext_vector_type(8))) short short8;
typedef __attribute__((ext_vector_type(2))) float f32x2;
typedef __attribute__((ext_vector_type(4))) float f32x4;
typedef __attribute__((ext_vector_type(4))) int i32x4;
typedef __attribute__((ext_vector_type(2))) int i32x2;
typedef __attribute__((ext_vector_type(4))) unsigned short us4;
typedef __attribute__((ext_vector_type(8))) unsigned short us8;
typedef __attribute__((ext_vector_type(4))) unsigned int u32x4;

#define N_NODES 50000
#define N_EDGES 800000
#define DIM 128
#define NINV (1.0f / 50000.0f)
#define SROW 136      /* LDS row stride (u16) */
#define NBKT 3125     /* node groups of 16: 50000/16 */
#define CAP 512       /* per-group capacity; mean 256, P(overflow) ~ e^-99 */
#define SUPN 256      /* nodes per superkey (16 groups); bin = dst>>8, local = dst&255 */
#define NSUP 196      /* ceil(50000/256); last superkey has 80 nodes (5 groups) */
#define SEGCAP 5120   /* segment entries per superkey; mean 4096, +16 sigma margin */
#define EPB 4096      /* edges per binning block (16/thread) */

__device__ __forceinline__ float bf2f(u16 u) {
    union { unsigned int i; float f; } v; v.i = ((unsigned int)u) << 16; return v.f;
}
__device__ __forceinline__ u16 f2bf(float f) {
    union { float f; unsigned int i; } v; v.f = f;
    return (u16)((v.i + 0x7FFFu + ((v.i >> 16) & 1u)) >> 16);
}

// ---------------- prep: pack B1/B2, split x, LDS-binned segmented edge bucketing ----
// blocks 0..15: pack B1; 16..31: pack B2; 32..32+splitB-1: split x (8 floats/thread);
// rest (196): 4096 edges/block (16/thread). LDS-bin into 196 superkeys (bin = dst>>8)
// with a 4-wave shfl scan; ONE segment-reserve global atomic per non-empty
// (block, superkey) (~38K total), reserve latency hidden under LDS scatter; coalesced
// ~84B run-writes into per-superkey segments. Entry = src<<8 | (dst & 255).
__global__ __launch_bounds__(256) void k_prep(
        const float* __restrict__ W1l, const float* __restrict__ W1r, u16* __restrict__ Bp1,
        const float* __restrict__ W2l, const float* __restrict__ W2r, u16* __restrict__ Bp2,
        const float* __restrict__ x, u16* __restrict__ xh, u8* __restrict__ xf8,
        const int* __restrict__ esrc, const int* __restrict__ edst,
        int* __restrict__ segCnt, unsigned* __restrict__ segBuf, int splitB) {
    int b = blockIdx.x;
    if (b < 32) {
        const float* Wl = (b < 16) ? W1l : W2l;
        const float* Wr = (b < 16) ? W1r : W2r;
        u16* Bp = (b < 16) ? Bp1 : Bp2;
        int idx = (b & 15) * 256 + threadIdx.x;      // 0..4095
        int lane = idx & 63;
        int kc = (idx >> 6) & 7;
        int nt = idx >> 9;
        int q = lane >> 4, nn = lane & 15;
        int col = nt * 16 + nn;
        #pragma unroll
        for (int j = 0; j < 8; ++j) {
            int k = kc * 32 + q * 8 + j;
            float v = (k < 128) ? Wl[k * 128 + col] : Wr[(k - 128) * 128 + col];
            Bp[(long)idx * 8 + j] = f2bf(v);
        }
    } else if (b < 32 + splitB) {
        long i8 = ((long)(b - 32) * 256 + threadIdx.x) * 8;
        f32x4 v0 = *(const f32x4*)(x + i8);
        f32x4 v1 = *(const f32x4*)(x + i8 + 4);
        us8 h;
        #pragma unroll
        for (int j = 0; j < 4; ++j) { h[j] = f2bf(v0[j]); h[4 + j] = f2bf(v1[j]); }
        *(us8*)(xh + i8) = h;
        int p0 = __builtin_amdgcn_cvt_pk_fp8_f32(v0[0], v0[1], 0, false);
        p0 = __builtin_amdgcn_cvt_pk_fp8_f32(v0[2], v0[3], p0, true);
        int p1 = __builtin_amdgcn_cvt_pk_fp8_f32(v1[0], v1[1], 0, false);
        p1 = __builtin_amdgcn_cvt_pk_fp8_f32(v1[2], v1[3], p1, true);
        i32x2 pp; pp[0] = p0; pp[1] = p1;
        *(i32x2*)(xf8 + i8) = pp;
    } else {
        __shared__ int sHistB[256], sScanB[256], sCurB[256], sBaseB[256];
        __shared__ int sWaveSum[4];
        __shared__ unsigned sStage[EPB];
        __shared__ u8 sBinOf[EPB];
        int tid = threadIdx.x;
        int hb = b - 32 - splitB;
        long e16 = (long)hb * EPB + tid * 16;
        bool val = e16 < N_EDGES;      // N_EDGES % 16 == 0: all-or-nothing per thread
        sHistB[tid] = 0;
        __syncthreads();
        unsigned ent[16]; int bin[16];
        if (val) {
            #pragma unroll
            for (int h4 = 0; h4 < 4; ++h4) {
                i32x4 d4 = *(const i32x4*)(edst + e16 + h4 * 4);
                i32x4 s4 = *(const i32x4*)(esrc + e16 + h4 * 4);
                #pragma unroll
                for (int j = 0; j < 4; ++j) {
                    unsigned dd = (unsigned)d4[j];
                    bin[h4 * 4 + j] = (int)(dd >> 8);
                    ent[h4 * 4 + j] = ((unsigned)s4[j] << 8) | (dd & 255u);
                }
            }
            #pragma unroll
            for (int j = 0; j < 16; ++j) atomicAdd(&sHistB[bin[j]], 1);
        }
        __syncthreads();
        // 4-wave parallel exclusive scan over 196 bins + cross-wave offsets
        int w = tid >> 6, lane = tid & 63;
        int v = (tid < NSUP) ? sHistB[tid] : 0;
        int sc = v;
        #pragma unroll
        for (int o = 1; o < 64; o <<= 1) {
            int t = __shfl_up(sc, o);
            if (lane >= o) sc += t;
        }
        if (lane == 63) sWaveSum[w] = sc;
        __syncthreads();
        if (tid == 0) {
            int acc = 0;
            #pragma unroll
            for (int i = 0; i < 4; ++i) { int t = sWaveSum[i]; sWaveSum[i] = acc; acc += t; }
        }
        __syncthreads();
        if (tid < NSUP) {
            int excl = sc - v + sWaveSum[w];
            sScanB[tid] = excl;
            sCurB[tid] = excl;
            // reserve segment space now; latency hides under the scatter below
            sBaseB[tid] = v ? atomicAdd(&segCnt[tid << 4], v) : 0;
        }
        __syncthreads();
        if (val) {
            #pragma unroll
            for (int j = 0; j < 16; ++j) {
                int p = atomicAdd(&sCurB[bin[j]], 1);
                sStage[p] = ent[j];
                sBinOf[p] = (u8)bin[j];
            }
        }
        __syncthreads();
        int tcount = sScanB[NSUP - 1] + sHistB[NSUP - 1];
        for (int p = tid; p < tcount; p += 256) {
            int bn = sBinOf[p];
            long ofs = (long)sBaseB[bn] + (p - sScanB[bn]);
            if (ofs < SEGCAP)
                segBuf[(long)bn * SEGCAP + ofs] = sStage[p];
        }
    }
}

// ---------------- per-superkey counting sort -> col_srt (group-CAP layout) + hdr ----
// 196 blocks x 512 threads (~1 block/CU on 3/4 of the chip); 10 entries/thread.
__global__ __launch_bounds__(512) void k_sort(
        const int* __restrict__ segCnt, const unsigned* __restrict__ segBuf,
        u16* __restrict__ col_srt, u16* __restrict__ hdr) {
    __shared__ int sHist[SUPN], sStart[SUPN], sCur[SUPN];
    int tid = threadIdx.x;
    int s = blockIdx.x;
    int nnodes = N_NODES - s * SUPN; if (nnodes > SUPN) nnodes = SUPN;
    int ngroups = nnodes >> 4;           // 16, or 5 for the last superkey
    int n = segCnt[s << 4]; if (n > SEGCAP) n = SEGCAP;
    if (tid < SUPN) { sHist[tid] = 0; sCur[tid] = 0; }
    __syncthreads();
    const unsigned* seg = segBuf + (long)s * SEGCAP;
    unsigned ent[10];
    #pragma unroll
    for (int i = 0; i < 10; ++i) {
        int idx = i * 512 + tid;                 // coalesced
        ent[i] = (idx < n) ? seg[idx] : 0xFFFFFFFFu;
    }
    #pragma unroll
    for (int i = 0; i < 10; ++i)
        if (ent[i] != 0xFFFFFFFFu) atomicAdd(&sHist[ent[i] & 255u], 1);
    __syncthreads();
    if (tid < ngroups) {
        int base = 0;
        int gb = (s * 16 + tid) * 32;
        #pragma unroll
        for (int i = 0; i < 16; ++i) {
            int node = tid * 16 + i;
            int d = sHist[node];
            int st_c = base < CAP ? base : CAP;
            int en_c = base + d < CAP ? base + d : CAP;
            sStart[node] = base;
            hdr[gb + i] = (u16)st_c;
            hdr[gb + 16 + i] = (u16)(en_c - st_c);
            base += d;
        }
    }
    __syncthreads();
    #pragma unroll
    for (int i = 0; i < 10; ++i) {
        unsigned e = ent[i];
        if (e != 0xFFFFFFFFu) {
            int node = (int)(e & 255u);
            int pos = atomicAdd(&sCur[node], 1);
            int ofs = sStart[node] + pos;
            if (ofs < CAP)
                col_srt[(long)(s * 16 + (node >> 4)) * CAP + ofs] = (u16)(e >> 8);
        }
    }
}

// decode 16 fp8 + accumulate — packed f32x2 path (v_pk_add_f32)
__device__ __forceinline__ void acc_row16(u32x4 w, f32x2 sum2[8]) {
    #pragma unroll
    for (int h = 0; h < 4; ++h) {
        sum2[2 * h]     += __builtin_amdgcn_cvt_pk_f32_fp8((int)w[h], false);
        sum2[2 * h + 1] += __builtin_amdgcn_cvt_pk_f32_fp8((int)w[h], true);
    }
}

// ---------------- fused AGG + GEMM + BN-stats (256 threads; proven round-8 shape) ----
// Both stages use this identical kernel: gather fp8 fq, root bf16 fh.
__global__ __launch_bounds__(256) void k_ag(
        const u8* __restrict__ fq, const u16* __restrict__ fh,
        const u16* __restrict__ hdr, const u16* __restrict__ col_srt,
        const u16* __restrict__ Bph, const float* __restrict__ bias,
        u16* __restrict__ h16, float* __restrict__ stats) {
    __shared__ u16 sA[16 * SROW];
    __shared__ __align__(16) u16 sIdx[CAP];
    int tid = threadIdx.x;
    long nodebase = (long)blockIdx.x * 16;       // 3125*16 == 50000 exact

    // stage sorted index list (1KB) into LDS
    if (tid < 64)
        *(us8*)(sIdx + tid * 8) = *(const us8*)(col_srt + (long)blockIdx.x * CAP + tid * 8);
    __syncthreads();

    // ---- phase 1: gather-mean (fp8, 16B/lane, even/odd edge split) ----
    {
        int grp = tid >> 4;          // node 0..15
        int g   = tid & 15;
        int sub = g >> 3;            // 0: even edges, 1: odd edges
        int gl  = g & 7;
        int d16 = gl * 16;           // dim base
        int st  = hdr[blockIdx.x * 32 + grp];
        int deg = hdr[blockIdx.x * 32 + 16 + grp];
        int s = st, e = st + deg;
        f32x2 sum2[8];
        #pragma unroll
        for (int p = 0; p < 8; ++p) sum2[p] = (f32x2){0.f, 0.f};
        int j = s + sub;
        for (; j + 6 < e; j += 8) {          // 4 loads in flight
            int i0 = sIdx[j], i1 = sIdx[j + 2], i2 = sIdx[j + 4], i3 = sIdx[j + 6];
            u32x4 w0 = *(const u32x4*)(fq + (long)i0 * DIM + d16);
            u32x4 w1 = *(const u32x4*)(fq + (long)i1 * DIM + d16);
            u32x4 w2 = *(const u32x4*)(fq + (long)i2 * DIM + d16);
            u32x4 w3 = *(const u32x4*)(fq + (long)i3 * DIM + d16);
            acc_row16(w0, sum2);
            acc_row16(w1, sum2);
            acc_row16(w2, sum2);
            acc_row16(w3, sum2);
        }
        for (; j < e; j += 2) {
            int i0 = sIdx[j];
            u32x4 w0 = *(const u32x4*)(fq + (long)i0 * DIM + d16);
            acc_row16(w0, sum2);
        }
        // combine even/odd halves (once per node)
        #pragma unroll
        for (int p = 0; p < 8; ++p) {
            sum2[p][0] += __shfl_xor(sum2[p][0], 8);
            sum2[p][1] += __shfl_xor(sum2[p][1], 8);
        }
        if (sub == 0) {
            float dn = (deg > 0) ? 1.f / (float)deg : 1.f;
            us8 r0, r1;
            #pragma unroll
            for (int k = 0; k < 8; ++k) {
                r0[k] = f2bf(sum2[k >> 1][k & 1] * dn);          // dims d16+0..7
                r1[k] = f2bf(sum2[4 + (k >> 1)][k & 1] * dn);    // dims d16+8..15
            }
            *(us8*)(sA + grp * SROW + d16) = r0;
            *(us8*)(sA + grp * SROW + d16 + 8) = r1;
        }
    }
    __syncthreads();

    // ---- phase 2: MFMA ----
    int cg = tid >> 6, lane = tid & 63;
    int q = lane >> 4, nn = lane & 15;
    long rc = nodebase + nn;

    short8 ah[8];
    #pragma unroll
    for (int kc = 0; kc < 4; ++kc)
        ah[kc] = *(const short8*)(sA + nn * SROW + kc * 32 + q * 8);
    #pragma unroll
    for (int kc = 0; kc < 4; ++kc) {
        int ko = kc * 32 + q * 8;
        us8 rv = *(const us8*)(fh + rc * DIM + ko);
        short8 t;
        #pragma unroll
        for (int j = 0; j < 8; ++j) t[j] = (short)rv[j];
        ah[4 + kc] = t;
    }

    f32x4 acc[2];
    acc[0] = (f32x4){0.f, 0.f, 0.f, 0.f};
    acc[1] = (f32x4){0.f, 0.f, 0.f, 0.f};

    #pragma unroll
    for (int kc = 0; kc < 8; ++kc) {
        #pragma unroll
        for (int nt = 0; nt < 2; ++nt) {
            int ntg = cg * 2 + nt;
            short8 bh = *(const short8*)(Bph + (((ntg * 8 + kc) * 64 + lane) << 3));
            acc[nt] = __builtin_amdgcn_mfma_f32_16x16x32_bf16(ah[kc], bh, acc[nt], 0, 0, 0);
        }
    }

    int bank = blockIdx.x & 7;
    #pragma unroll
    for (int nt = 0; nt < 2; ++nt) {
        int col = cg * 32 + nt * 16 + nn;
        float bv = bias[col];
        float ps = 0.f, pq = 0.f;
        #pragma unroll
        for (int r = 0; r < 4; ++r) {
            float v = acc[nt][r] + bv;
            long idx = (nodebase + q * 4 + r) * DIM + col;
            h16[idx] = f2bf(v);
            ps += v; pq += v * v;
        }
        ps += __shfl_xor(ps, 16);
        ps += __shfl_xor(ps, 32);
        pq += __shfl_xor(pq, 16);
        pq += __shfl_xor(pq, 32);
        if (q == 0) {
            atomicAdd(&stats[bank * 512 + col], ps);
            atomicAdd(&stats[bank * 512 + 256 + col], pq);
        }
    }
}

// ---------------- h_act = relu(bn1(h1)) once per node -> bf16 (root) + fp8 (gather) ----
__global__ __launch_bounds__(256) void k_act(
        const u16* __restrict__ h, const float* __restrict__ stats,
        const float* __restrict__ g, const float* __restrict__ bt,
        u16* __restrict__ outh, u8* __restrict__ outq) {
    __shared__ float acS[256];
    int tid = threadIdx.x;
    if (tid < 128) {
        float s = 0.f, qq = 0.f;
        #pragma unroll
        for (int b = 0; b < 8; ++b) {
            s  += stats[b * 512 + tid];
            qq += stats[b * 512 + 256 + tid];
        }
        float mu = s * NINV;
        float var = qq * NINV - mu * mu;
        float a = g[tid] * rsqrtf(var + 1e-5f);
        acS[tid] = a;
        acS[128 + tid] = bt[tid] - mu * a;
    }
    __syncthreads();
    long i8 = ((long)blockIdx.x * 256 + tid) * 8;
    int c = (int)(i8 & 127);
    us8 hv = *(const us8*)(h + i8);
    us8 r;
    float v[8];
    #pragma unroll
    for (int j = 0; j < 8; ++j) {
        float t = bf2f(hv[j]) * acS[c + j] + acS[128 + c + j];
        t = t > 0.f ? t : 0.f;
        v[j] = t;
        r[j] = f2bf(t);
    }
    *(us8*)(outh + i8) = r;
    int p0 = __builtin_amdgcn_cvt_pk_fp8_f32(v[0], v[1], 0, false);
    p0 = __builtin_amdgcn_cvt_pk_fp8_f32(v[2], v[3], p0, true);
    int p1 = __builtin_amdgcn_cvt_pk_fp8_f32(v[4], v[5], 0, false);
    p1 = __builtin_amdgcn_cvt_pk_fp8_f32(v[6], v[7], p1, true);
    i32x2 pp; pp[0] = p0; pp[1] = p1;
    *(i32x2*)(outq + i8) = pp;
}

// out = relu(bn(h)+x); coeffs computed in-block from banked stats
__global__ __launch_bounds__(256) void k_bn_add_relu(
        const u16* __restrict__ h, const float* __restrict__ stats,
        const float* __restrict__ g, const float* __restrict__ bt,
        const float* __restrict__ x, float* __restrict__ outv) {
    __shared__ float acS[256];
    int tid = threadIdx.x;
    if (tid < 128) {
        float s = 0.f, qq = 0.f;
        #pragma unroll
        for (int b = 0; b < 8; ++b) {
            s  += stats[b * 512 + tid];
            qq += stats[b * 512 + 256 + tid];
        }
        float mu = s * NINV;
        float var = qq * NINV - mu * mu;
        float a = g[tid] * rsqrtf(var + 1e-5f);
        acS[tid] = a;
        acS[128 + tid] = bt[tid] - mu * a;
    }
    __syncthreads();
    long i8 = ((long)blockIdx.x * 256 + tid) * 8;
    int c = (int)(i8 & 127);
    us8 hv = *(const us8*)(h + i8);
    f32x4 x0 = *(const f32x4*)(x + i8);
    f32x4 x1 = *(const f32x4*)(x + i8 + 4);
    f32x4 r0, r1;
    #pragma unroll
    for (int j = 0; j < 4; ++j) {
        float v = bf2f(hv[j]) * acS[c + j] + acS[128 + c + j] + x0[j];
        r0[j] = v > 0.f ? v : 0.f;
        float w = bf2f(hv[4 + j]) * acS[c + 4 + j] + acS[128 + c + 4 + j] + x1[j];
        r1[j] = w > 0.f ? w : 0.f;
    }
    *(f32x4*)(outv + i8) = r0;
    *(f32x4*)(outv + i8 + 4) = r1;
}

extern "C" void kernel_launch(void* const* d_in, const int* in_sizes, int n_in,
                              void* d_out, int out_size, void* d_ws, size_t ws_size,
                              hipStream_t stream) {
    (void)in_sizes; (void)n_in; (void)out_size; (void)ws_size;
    const float* x   = (const float*)d_in[0];
    const int*   ei  = (const int*)d_in[1];
    const float* W1l = (const float*)d_in[2];
    const float* b1  = (const float*)d_in[3];
    const float* W1r = (const float*)d_in[4];
    const float* g1  = (const float*)d_in[5];
    const float* bt1 = (const float*)d_in[6];
    const float* W2l = (const float*)d_in[7];
    const float* b2  = (const float*)d_in[8];
    const float* W2r = (const float*)d_in[9];
    const float* g2  = (const float*)d_in[10];
    const float* bt2 = (const float*)d_in[11];
    float* out = (float*)d_out;

    const int* esrc = ei;
    const int* edst = ei + N_EDGES;

    char* ws = (char*)d_ws;
    size_t off = 0;
    auto alloc = [&](size_t bytes) { size_t p = off; off = (off + bytes + 255) & ~(size_t)255; return p; };
    float* stats1  = (float*)(ws + alloc(4096 * 4));   // 8 banks x 512 (sum@+col, sumsq@+256+col)
    float* stats2  = (float*)(ws + alloc(4096 * 4));
    int*   segCnt  = (int*)  (ws + alloc(256 * 16 * 4));   // 1 counter per 64B line
    size_t zero_bytes = off;                       // everything above must be zeroed
    unsigned* segBuf = (unsigned*)(ws + alloc((size_t)NSUP * SEGCAP * 4));
    u16*   col_srt = (u16*)  (ws + alloc((size_t)NBKT * CAP * 2));
    u16*   hdr     = (u16*)  (ws + alloc((size_t)NBKT * 32 * 2));
    u16*   xh      = (u16*)  (ws + alloc((size_t)N_NODES * DIM * 2));
    u8*    xf8     = (u8*)   (ws + alloc((size_t)N_NODES * DIM));
    u16*   hb1     = (u16*)  (ws + alloc((size_t)N_NODES * DIM * 2));  // raw h1 bf16
    u16*   hah     = (u16*)  (ws + alloc((size_t)N_NODES * DIM * 2));  // h_act bf16
    u8*    haf8    = (u8*)   (ws + alloc((size_t)N_NODES * DIM));     // h_act fp8
    u16*   hb2     = (u16*)  (ws + alloc((size_t)N_NODES * DIM * 2));  // raw h2 bf16
    u16*   Bp1h    = (u16*)  (ws + alloc(256 * 128 * 2));
    u16*   Bp2h    = (u16*)  (ws + alloc(256 * 128 * 2));

    hipMemsetAsync(ws, 0, zero_bytes, stream);

    const int AGB = N_NODES / 16;                    // 3125 exact
    const int EWB8 = (int)(((long)N_NODES * DIM) / 2048);  // 3125 exact (8 f32/thread)
    const int EDGB = (N_EDGES + EPB - 1) / EPB;      // 196 (16 edges/thread)
    const int PREPB = 32 + EWB8 + EDGB;              // pack + split + binned append

    // prep: pack both B + split x (bf16 + fp8) + LDS-binned segmented bucketing
    k_prep<<<PREPB, 256, 0, stream>>>(W1l, W1r, Bp1h, W2l, W2r, Bp2h, x, xh, xf8,
                                      esrc, edst, segCnt, segBuf, EWB8);

    // per-superkey counting sort -> col_srt (group-CAP layout) + hdr
    k_sort<<<NSUP, 512, 0, stream>>>(segCnt, segBuf, col_srt, hdr);

    // stage 1: fused agg+gemm on x (fp8 gather, bf16 root); writes h1 bf16 + stats1
    k_ag<<<AGB, 256, 0, stream>>>(xf8, xh, hdr, col_srt, Bp1h, b1, hb1, stats1);

    // h_act = relu(bn1(h1)) once per node -> bf16 + fp8
    k_act<<<EWB8, 256, 0, stream>>>(hb1, stats1, g1, bt1, hah, haf8);

    // stage 2: fused agg+gemm on h_act; writes h2 bf16 + stats2
    k_ag<<<AGB, 256, 0, stream>>>(haf8, hah, hdr, col_srt, Bp2h, b2, hb2, stats2);

    // epilogue: out = relu(bn(h2) + x), coeffs from stats2
    k_bn_add_relu<<<EWB8, 256, 0, stream>>>(hb2, stats2, g2, bt2, x, out);
}